// Round 14
// baseline (216.568 us; speedup 1.0000x reference)
//
#include <hip/hip_runtime.h>
#include <hip/hip_bf16.h>
#include <stdint.h>

typedef __bf16 bf16_t;
typedef __bf16 v8bf  __attribute__((ext_vector_type(8)));
typedef __bf16 v4bf  __attribute__((ext_vector_type(4)));
typedef float  f32x4 __attribute__((ext_vector_type(4)));
typedef unsigned short u16x8 __attribute__((ext_vector_type(8)));

#define B_   2
#define T_   2048
#define D_   768
#define H_   12
#define DH_  64
#define N3_  2304
#define M_   4096
#define SPLIT_ 2

// async global->LDS, 16B per lane; LDS dest must be wave-uniform base (HW adds lane*16)
__device__ __forceinline__ void gll16(const void* g, void* l) {
  __builtin_amdgcn_global_load_lds(
      (const __attribute__((address_space(1))) void*)g,
      (__attribute__((address_space(3))) void*)l,
      16, 0, 0);
}

__device__ __forceinline__ float bf2f(unsigned short u) {
  union { unsigned u; float f; } x; x.u = ((unsigned)u) << 16; return x.f;
}

// ---------------- 1. convert x: fp32 -> bf16 ----------------
__global__ __launch_bounds__(256) void k_conv_x(const float* __restrict__ x,
                                                bf16_t* __restrict__ xb, int n4) {
  int i = blockIdx.x * 256 + threadIdx.x;
  if (i < n4) {
    float4 v = ((const float4*)x)[i];
    v4bf o = {(bf16_t)v.x, (bf16_t)v.y, (bf16_t)v.z, (bf16_t)v.w};
    *(v4bf*)(xb + (size_t)i * 4) = o;
  }
}

// ---------------- 2. convert + transpose W: [768,2304] fp32 -> Wt [2304,768] bf16 ----
__global__ __launch_bounds__(256) void k_conv_wt(const float* __restrict__ W,
                                                 bf16_t* __restrict__ Wt) {
  __shared__ bf16_t tile[64 * 64];
  const int tid = threadIdx.x;
  const int n0 = blockIdx.x * 64;   // col tile of W (row of Wt), 36 tiles
  const int k0 = blockIdx.y * 64;   // row tile of W, 12 tiles
  #pragma unroll
  for (int rr = 0; rr < 4; ++rr) {
    int k  = rr * 16 + (tid >> 4);
    int gr = tid & 15;
    float4 v = *(const float4*)(W + (size_t)(k0 + k) * N3_ + n0 + gr * 4);
    v4bf o = {(bf16_t)v.x, (bf16_t)v.y, (bf16_t)v.z, (bf16_t)v.w};
    *(v4bf*)(tile + k * 64 + ((gr ^ (k & 15)) << 2)) = o;
  }
  __syncthreads();
  const int n = tid & 63, q = tid >> 6;
  bf16_t outv[16] __attribute__((aligned(16)));
  #pragma unroll
  for (int tt = 0; tt < 16; ++tt) {
    int k = q * 16 + tt;
    outv[tt] = tile[k * 64 + (((n >> 2) ^ (k & 15)) << 2) + (n & 3)];
  }
  bf16_t* dst = Wt + (size_t)(n0 + n) * D_ + k0 + q * 16;
  *(u16x8*)dst       = *(const u16x8*)outv;
  *((u16x8*)dst + 1) = *(const u16x8*)(outv + 8);
}

// ---------------- 3. GEMM: qkv = xb @ Wt^T + bias; V blocks write Vt directly ----
// R11-proven serial-staging structure (BK=32, m97 pattern) — do not touch.
// Q columns (n < 768) pre-scaled by DH^-0.5 * log2(e); V columns (n >= 1536)
// written transposed+column-permuted to vt so attention's P stays in-register.
#define BK 32
__global__ __launch_bounds__(256) void k_gemm(const bf16_t* __restrict__ A,   // [4096,768]
                                              const bf16_t* __restrict__ Bt,  // [2304,768]
                                              const float*  __restrict__ bias,
                                              bf16_t* __restrict__ Cq,        // [4096,2304]
                                              bf16_t* __restrict__ vt) {      // [24,64,2048]
  __shared__ bf16_t As[128 * BK];
  __shared__ bf16_t Bs[128 * BK];
  const int tid  = threadIdx.x;
  const int wave = tid >> 6, lane = tid & 63;
  const int g = lane >> 4, c = lane & 15;
  const int wy = wave >> 1, wx = wave & 1;
  const int bm = blockIdx.y * 128, bn = blockIdx.x * 128;

  const f32x4 zf = {0.f, 0.f, 0.f, 0.f};
  f32x4 acc[4][4];
  #pragma unroll
  for (int i = 0; i < 4; ++i)
    #pragma unroll
    for (int j = 0; j < 4; ++j) acc[i][j] = zf;

  const int rA = tid >> 2;          // row within 64-row half-tile
  const int kc = (tid & 3) * 8;     // k-element within BK

  for (int k0 = 0; k0 < D_; k0 += BK) {
    __syncthreads();
    #pragma unroll
    for (int cc = 0; cc < 2; ++cc) {
      gll16(A  + (size_t)(bm + cc * 64 + rA) * D_ + k0 + kc,
            (char*)As + cc * 4096 + wave * 1024);
      gll16(Bt + (size_t)(bn + cc * 64 + rA) * D_ + k0 + kc,
            (char*)Bs + cc * 4096 + wave * 1024);
    }
    __syncthreads();
    v8bf af[4], bfr[4];
    #pragma unroll
    for (int mi = 0; mi < 4; ++mi)
      af[mi] = *(const v8bf*)(As + (wy * 64 + mi * 16 + c) * BK + g * 8);
    #pragma unroll
    for (int ni = 0; ni < 4; ++ni)
      bfr[ni] = *(const v8bf*)(Bs + (wx * 64 + ni * 16 + c) * BK + g * 8);
    #pragma unroll
    for (int mi = 0; mi < 4; ++mi)
      #pragma unroll
      for (int ni = 0; ni < 4; ++ni)
        acc[mi][ni] = __builtin_amdgcn_mfma_f32_16x16x32_bf16(af[mi], bfr[ni], acc[mi][ni], 0, 0, 0);
  }

  if (bn >= 2 * D_) {
    // V block: write transposed + column-permuted into vt (4-elem granule kept)
    const int hb = ((bn - 2 * D_) >> 6) + wx;          // head, block/wave-uniform
    #pragma unroll
    for (int ni = 0; ni < 4; ++ni) {
      float bv = bias[bn + wx * 64 + ni * 16 + c];
      const int d = ni * 16 + c;
      #pragma unroll
      for (int mi = 0; mi < 4; ++mi) {
        int row = bm + wy * 64 + mi * 16 + g * 4;      // global row, 4-aligned
        int b = row >> 11, t = row & (T_ - 1);
        int tl = t & 63;
        // s = [b5=kk | b4b3=g | b2=ih | b1b0=j] from t = [kk|ih|g|j]
        int sp = (t & ~63) | (tl & 35) | ((tl & 12) << 1) | ((tl & 16) >> 2);
        v4bf o = {(bf16_t)(acc[mi][ni][0] + bv), (bf16_t)(acc[mi][ni][1] + bv),
                  (bf16_t)(acc[mi][ni][2] + bv), (bf16_t)(acc[mi][ni][3] + bv)};
        *(v4bf*)(vt + ((size_t)((b * H_ + hb) * DH_ + d)) * T_ + sp) = o;
      }
    }
  } else {
    // Q/K block: Q columns get softmax scale folded in (768 % 128 == 0)
    const float qscale = (bn < D_) ? 0.18033688011112042f : 1.0f;  // 0.125 * log2(e)
    #pragma unroll
    for (int ni = 0; ni < 4; ++ni) {
      float bv = bias[bn + wx * 64 + ni * 16 + c];
      #pragma unroll
      for (int mi = 0; mi < 4; ++mi) {
        int row = bm + wy * 64 + mi * 16 + g * 4;
        bf16_t* d0 = Cq + (size_t)row * N3_ + bn + wx * 64 + ni * 16 + c;
        #pragma unroll
        for (int j = 0; j < 4; ++j)
          d0[(size_t)j * N3_] = (bf16_t)((acc[mi][ni][j] + bv) * qscale);
      }
    }
  }
}

// ---------------- 5. flash attention: ZERO-LDS, direct global->reg fragments -------
// K/V per (b,h,z) is 128+128 KB — L2-resident, and all 4 waves of a block read
// the same 16KB tile within a short window (L1 catches the redundancy). So skip
// LDS staging entirely (catalog: "don't stage what L2-fits", m169): each lane
// global-loads its MFMA A-fragments for K and V directly. No barriers at all —
// waves fully independent. V's key permutation lives in vtb storage (k_gemm),
// so P stays in-register with zero swizzle logic. p = 2^s, unnormalized.
template<int SPLIT>
__global__ __launch_bounds__(256) void k_attn(const bf16_t* __restrict__ qkv,
                                              const bf16_t* __restrict__ vt,
                                              float* __restrict__ outp,
                                              float* __restrict__ lpart) {
  const int tid  = threadIdx.x;
  const int wave = tid >> 6, lane = tid & 63;
  const int g = lane >> 4, c = lane & 15;
  const int qt = blockIdx.x;           // 32 q-tiles of 64 rows
  const int bh = blockIdx.y;           // 24
  const int z  = (SPLIT > 1) ? blockIdx.z : 0;
  const int b = bh / H_, h = bh - b * H_;
  const int r0 = z * (T_ / SPLIT);     // key-range base

  // hoisted Q fragments: lane holds Q[q = c][d = 8g..8g+7 (+32)] (pre-scaled)
  v8bf aq[2];
  {
    const bf16_t* qb = qkv + ((size_t)(b * T_ + qt * 64 + wave * 16 + c)) * N3_ + h * DH_ + g * 8;
    aq[0] = *(const v8bf*)qb;
    aq[1] = *(const v8bf*)(qb + 32);
  }
  float lsum = 0.f;
  const f32x4 zf = {0.f, 0.f, 0.f, 0.f};
  f32x4 oacc[4];                            // O^T[d = ni*16+g*4+j][q = c]
  #pragma unroll
  for (int ni = 0; ni < 4; ++ni) oacc[ni] = zf;

  // per-lane fragment bases (tile 0): K A-frag row = key = ni*16+c, 16B at d = kk*32+g*8
  //                                   V A-frag row = d = ni*16+c, 16B at slot = kk*32+g*8
  const bf16_t* kb = qkv + ((size_t)(b * T_ + r0 + c)) * N3_ + D_ + h * DH_ + g * 8;
  const bf16_t* vb = vt + ((size_t)(bh * DH_ + c)) * T_ + r0 + g * 8;

  const int NT = T_ / (64 * SPLIT);
  for (int kt = 0; kt < NT; ++kt) {
    // issue all 16 fragment loads; V loads stay in flight under QK^T + exp
    v8bf kf[2][4], vf[2][4];
    #pragma unroll
    for (int kk = 0; kk < 2; ++kk)
      #pragma unroll
      for (int ni = 0; ni < 4; ++ni)
        kf[kk][ni] = *(const v8bf*)(kb + (size_t)ni * 16 * N3_ + kk * 32);
    #pragma unroll
    for (int kk = 0; kk < 2; ++kk)
      #pragma unroll
      for (int ni = 0; ni < 4; ++ni)
        vf[kk][ni] = *(const v8bf*)(vb + (size_t)ni * 16 * T_ + kk * 32);
    kb += 64 * (size_t)N3_;
    vb += 64;

    // S^T = K·Q^T: lane holds S[q=c][key = ni*16 + g*4 + j]
    f32x4 s[4] = {zf, zf, zf, zf};
    __builtin_amdgcn_s_setprio(1);
    #pragma unroll
    for (int kk = 0; kk < 2; ++kk)
      #pragma unroll
      for (int ni = 0; ni < 4; ++ni)
        s[ni] = __builtin_amdgcn_mfma_f32_16x16x32_bf16(kf[kk][ni], aq[kk], s[ni], 0, 0, 0);
    __builtin_amdgcn_s_setprio(0);

    // unnormalized softmax: p = 2^s, packed straight into the PV B-fragments
    float rsub = 0.f;
    v8bf apk[2];
    #pragma unroll
    for (int ni = 0; ni < 4; ++ni) {
      float p0 = __builtin_amdgcn_exp2f(s[ni][0]);
      float p1 = __builtin_amdgcn_exp2f(s[ni][1]);
      float p2 = __builtin_amdgcn_exp2f(s[ni][2]);
      float p3 = __builtin_amdgcn_exp2f(s[ni][3]);
      rsub += (p0 + p1) + (p2 + p3);
      const int kkh = ni >> 1, off = (ni & 1) * 4;
      apk[kkh][off + 0] = (bf16_t)p0;
      apk[kkh][off + 1] = (bf16_t)p1;
      apk[kkh][off + 2] = (bf16_t)p2;
      apk[kkh][off + 3] = (bf16_t)p3;
    }
    lsum += rsub;

    // O^T += V^T·P^T (V storage pre-permuted so apk is the exact B-fragment)
    __builtin_amdgcn_s_setprio(1);
    #pragma unroll
    for (int kk = 0; kk < 2; ++kk)
      #pragma unroll
      for (int ni = 0; ni < 4; ++ni)
        oacc[ni] = __builtin_amdgcn_mfma_f32_16x16x32_bf16(vf[kk][ni], apk[kk], oacc[ni], 0, 0, 0);
    __builtin_amdgcn_s_setprio(0);
  }

  // epilogue
  lsum += __shfl_xor(lsum, 16);
  lsum += __shfl_xor(lsum, 32);
  const float inv = 1.0f / lsum;
  const int q = qt * 64 + wave * 16 + c;
  if (SPLIT > 1) {
    if (g == 0) lpart[(size_t)z * (B_ * H_ * T_) + (b * H_ + h) * T_ + q] = lsum;
    bf16_t* ob = (bf16_t*)outp + ((size_t)z * M_ * D_ + ((size_t)(b * T_ + q)) * D_ + h * DH_);
    #pragma unroll
    for (int ni = 0; ni < 4; ++ni) {
      v4bf o4 = {(bf16_t)(oacc[ni][0] * inv), (bf16_t)(oacc[ni][1] * inv),
                 (bf16_t)(oacc[ni][2] * inv), (bf16_t)(oacc[ni][3] * inv)};
      *(v4bf*)(ob + ni * 16 + g * 4) = o4;
    }
  } else {
    float* ob = outp + ((size_t)(b * T_ + q)) * D_ + h * DH_;
    #pragma unroll
    for (int ni = 0; ni < 4; ++ni) {
      float4 o4 = {oacc[ni][0] * inv, oacc[ni][1] * inv, oacc[ni][2] * inv, oacc[ni][3] * inv};
      *(float4*)(ob + ni * 16 + g * 4) = o4;
    }
  }
}

// ---------------- 6. combine SPLIT parts: out = sum(o_z * l_z) / sum(l_z) ----------
__global__ __launch_bounds__(256) void k_combine(const bf16_t* __restrict__ op,
                                                 const float* __restrict__ lp,
                                                 float* __restrict__ out) {
  const int i = blockIdx.x * 256 + threadIdx.x;   // 8-elem group, < 393216
  const int e  = i * 8;
  const int tg = e / D_;                 // global row in [0, B*T)
  const int d  = e - tg * D_;
  const int h  = d >> 6;
  const int b  = tg >> 11;
  const int t  = tg & (T_ - 1);
  const int li = (b * H_ + h) * T_ + t;
  float acc[8] = {0.f, 0.f, 0.f, 0.f, 0.f, 0.f, 0.f, 0.f};
  float ltot = 0.f;
  #pragma unroll
  for (int z = 0; z < SPLIT_; ++z) {
    const float lz = lp[(size_t)z * (B_ * H_ * T_) + li];
    ltot += lz;
    u16x8 u = *(const u16x8*)(op + (size_t)z * M_ * D_ + e);
    #pragma unroll
    for (int j = 0; j < 8; ++j) acc[j] += bf2f(u[j]) * lz;
  }
  const float inv = 1.0f / ltot;
  float4 o0 = {acc[0] * inv, acc[1] * inv, acc[2] * inv, acc[3] * inv};
  float4 o1 = {acc[4] * inv, acc[5] * inv, acc[6] * inv, acc[7] * inv};
  *(float4*)(out + e)     = o0;
  *(float4*)(out + e + 4) = o1;
}

extern "C" void kernel_launch(void* const* d_in, const int* in_sizes, int n_in,
                              void* d_out, int out_size, void* d_ws, size_t ws_size,
                              hipStream_t stream) {
  const float* x    = (const float*)d_in[0];
  const float* W    = (const float*)d_in[1];
  const float* bias = (const float*)d_in[2];
  float* out = (float*)d_out;
  char* ws = (char*)d_ws;
  bf16_t* xb    = (bf16_t*)(ws);                 // 4096*768*2   = 6,291,456
  bf16_t* wt    = (bf16_t*)(ws + 6291456);       // 2304*768*2   = 3,538,944
  bf16_t* qkvb  = (bf16_t*)(ws + 9830400);       // 4096*2304*2  = 18,874,368
  bf16_t* vtb   = (bf16_t*)(ws + 28704768);      // 24*64*2048*2 = 6,291,456
  bf16_t* opart = (bf16_t*)(ws + 34996224);      // 2*4096*768*2 = 12,582,912
  float*  lpart = (float*)(ws + 47579136);       // 2*49152*4    = 393,216
  const size_t need_split = 47972352;

  k_conv_x <<<dim3(3072),    dim3(256), 0, stream>>>(x, xb, (M_ * D_) / 4);
  k_conv_wt<<<dim3(36, 12),  dim3(256), 0, stream>>>(W, wt);
  k_gemm   <<<dim3(18, 32),  dim3(256), 0, stream>>>(xb, wt, bias, qkvb, vtb);
  if (ws_size >= need_split) {
    k_attn<SPLIT_><<<dim3(32, 24, SPLIT_), dim3(256), 0, stream>>>(qkvb, vtb, (float*)opart, lpart);
    k_combine<<<dim3(1536), dim3(256), 0, stream>>>(opart, lpart, out);
  } else {
    k_attn<1><<<dim3(32, 24), dim3(256), 0, stream>>>(qkvb, vtb, out, nullptr);
  }
}

// Round 15
// 76.419 us; speedup vs baseline: 2.8340x; 2.8340x over previous
//
#include <hip/hip_runtime.h>
#include <hip/hip_bf16.h>
#include <stdint.h>

typedef __bf16 bf16_t;
typedef __bf16 v8bf  __attribute__((ext_vector_type(8)));
typedef __bf16 v4bf  __attribute__((ext_vector_type(4)));
typedef float  f32x4 __attribute__((ext_vector_type(4)));
typedef unsigned short u16x8 __attribute__((ext_vector_type(8)));

#define B_   2
#define T_   2048
#define D_   768
#define H_   12
#define DH_  64
#define N3_  2304
#define M_   4096

// async global->LDS, 16B per lane; LDS dest must be wave-uniform base (HW adds lane*16)
__device__ __forceinline__ void gll16(const void* g, void* l) {
  __builtin_amdgcn_global_load_lds(
      (const __attribute__((address_space(1))) void*)g,
      (__attribute__((address_space(3))) void*)l,
      16, 0, 0);
}

__device__ __forceinline__ float bf2f(unsigned short u) {
  union { unsigned u; float f; } x; x.u = ((unsigned)u) << 16; return x.f;
}

// ---------------- 1. convert x: fp32 -> bf16 ----------------
__global__ __launch_bounds__(256) void k_conv_x(const float* __restrict__ x,
                                                bf16_t* __restrict__ xb, int n4) {
  int i = blockIdx.x * 256 + threadIdx.x;
  if (i < n4) {
    float4 v = ((const float4*)x)[i];
    v4bf o = {(bf16_t)v.x, (bf16_t)v.y, (bf16_t)v.z, (bf16_t)v.w};
    *(v4bf*)(xb + (size_t)i * 4) = o;
  }
}

// ---------------- 2. convert + transpose W: [768,2304] fp32 -> Wt [2304,768] bf16 ----
__global__ __launch_bounds__(256) void k_conv_wt(const float* __restrict__ W,
                                                 bf16_t* __restrict__ Wt) {
  __shared__ bf16_t tile[64 * 64];
  const int tid = threadIdx.x;
  const int n0 = blockIdx.x * 64;   // col tile of W (row of Wt), 36 tiles
  const int k0 = blockIdx.y * 64;   // row tile of W, 12 tiles
  #pragma unroll
  for (int rr = 0; rr < 4; ++rr) {
    int k  = rr * 16 + (tid >> 4);
    int gr = tid & 15;
    float4 v = *(const float4*)(W + (size_t)(k0 + k) * N3_ + n0 + gr * 4);
    v4bf o = {(bf16_t)v.x, (bf16_t)v.y, (bf16_t)v.z, (bf16_t)v.w};
    *(v4bf*)(tile + k * 64 + ((gr ^ (k & 15)) << 2)) = o;
  }
  __syncthreads();
  const int n = tid & 63, q = tid >> 6;
  bf16_t outv[16] __attribute__((aligned(16)));
  #pragma unroll
  for (int tt = 0; tt < 16; ++tt) {
    int k = q * 16 + tt;
    outv[tt] = tile[k * 64 + (((n >> 2) ^ (k & 15)) << 2) + (n & 3)];
  }
  bf16_t* dst = Wt + (size_t)(n0 + n) * D_ + k0 + q * 16;
  *(u16x8*)dst       = *(const u16x8*)outv;
  *((u16x8*)dst + 1) = *(const u16x8*)(outv + 8);
}

// ---------------- 3. GEMM: qkv = xb @ Wt^T + bias; V blocks write Vt directly ----
// R11-proven serial-staging structure (BK=32, m97 pattern) — do not touch.
// Q columns (n < 768) pre-scaled by DH^-0.5 * log2(e); V columns (n >= 1536)
// written transposed+column-permuted to vt so attention's P stays in-register.
#define BK 32
__global__ __launch_bounds__(256) void k_gemm(const bf16_t* __restrict__ A,   // [4096,768]
                                              const bf16_t* __restrict__ Bt,  // [2304,768]
                                              const float*  __restrict__ bias,
                                              bf16_t* __restrict__ Cq,        // [4096,2304]
                                              bf16_t* __restrict__ vt) {      // [24,64,2048]
  __shared__ bf16_t As[128 * BK];
  __shared__ bf16_t Bs[128 * BK];
  const int tid  = threadIdx.x;
  const int wave = tid >> 6, lane = tid & 63;
  const int g = lane >> 4, c = lane & 15;
  const int wy = wave >> 1, wx = wave & 1;
  const int bm = blockIdx.y * 128, bn = blockIdx.x * 128;

  const f32x4 zf = {0.f, 0.f, 0.f, 0.f};
  f32x4 acc[4][4];
  #pragma unroll
  for (int i = 0; i < 4; ++i)
    #pragma unroll
    for (int j = 0; j < 4; ++j) acc[i][j] = zf;

  const int rA = tid >> 2;          // row within 64-row half-tile
  const int kc = (tid & 3) * 8;     // k-element within BK

  for (int k0 = 0; k0 < D_; k0 += BK) {
    __syncthreads();
    #pragma unroll
    for (int cc = 0; cc < 2; ++cc) {
      gll16(A  + (size_t)(bm + cc * 64 + rA) * D_ + k0 + kc,
            (char*)As + cc * 4096 + wave * 1024);
      gll16(Bt + (size_t)(bn + cc * 64 + rA) * D_ + k0 + kc,
            (char*)Bs + cc * 4096 + wave * 1024);
    }
    __syncthreads();
    v8bf af[4], bfr[4];
    #pragma unroll
    for (int mi = 0; mi < 4; ++mi)
      af[mi] = *(const v8bf*)(As + (wy * 64 + mi * 16 + c) * BK + g * 8);
    #pragma unroll
    for (int ni = 0; ni < 4; ++ni)
      bfr[ni] = *(const v8bf*)(Bs + (wx * 64 + ni * 16 + c) * BK + g * 8);
    #pragma unroll
    for (int mi = 0; mi < 4; ++mi)
      #pragma unroll
      for (int ni = 0; ni < 4; ++ni)
        acc[mi][ni] = __builtin_amdgcn_mfma_f32_16x16x32_bf16(af[mi], bfr[ni], acc[mi][ni], 0, 0, 0);
  }

  if (bn >= 2 * D_) {
    // V block: write transposed + column-permuted into vt (4-elem granule kept)
    const int hb = ((bn - 2 * D_) >> 6) + wx;          // head, block/wave-uniform
    #pragma unroll
    for (int ni = 0; ni < 4; ++ni) {
      float bv = bias[bn + wx * 64 + ni * 16 + c];
      const int d = ni * 16 + c;
      #pragma unroll
      for (int mi = 0; mi < 4; ++mi) {
        int row = bm + wy * 64 + mi * 16 + g * 4;      // global row, 4-aligned
        int b = row >> 11, t = row & (T_ - 1);
        int tl = t & 63;
        // s = [b5=kk | b4b3=g | b2=ih | b1b0=j] from t = [kk|ih|g|j]
        int sp = (t & ~63) | (tl & 35) | ((tl & 12) << 1) | ((tl & 16) >> 2);
        v4bf o = {(bf16_t)(acc[mi][ni][0] + bv), (bf16_t)(acc[mi][ni][1] + bv),
                  (bf16_t)(acc[mi][ni][2] + bv), (bf16_t)(acc[mi][ni][3] + bv)};
        *(v4bf*)(vt + ((size_t)((b * H_ + hb) * DH_ + d)) * T_ + sp) = o;
      }
    }
  } else {
    // Q/K block: Q columns get softmax scale folded in (768 % 128 == 0)
    const float qscale = (bn < D_) ? 0.18033688011112042f : 1.0f;  // 0.125 * log2(e)
    #pragma unroll
    for (int ni = 0; ni < 4; ++ni) {
      float bv = bias[bn + wx * 64 + ni * 16 + c];
      #pragma unroll
      for (int mi = 0; mi < 4; ++mi) {
        int row = bm + wy * 64 + mi * 16 + g * 4;
        bf16_t* d0 = Cq + (size_t)row * N3_ + bn + wx * 64 + ni * 16 + c;
        #pragma unroll
        for (int j = 0; j < 4; ++j)
          d0[(size_t)j * N3_] = (bf16_t)((acc[mi][ni][j] + bv) * qscale);
      }
    }
  }
}

// ---------------- 5. flash attention: P in-register, dbuf K/V, 1 barrier/tile ------
// R11 kernel, byte-identical (confirmed best: 43.7us, MfmaUtil 23.7, 0 conflicts).
// SPLIT=1: full key range per block, writes fp32 out directly — no combine pass
// (split's epilogue bytes are identical; only the combine kernel is saved).
template<int SPLIT>
__global__ __launch_bounds__(256) void k_attn(const bf16_t* __restrict__ qkv,
                                              const bf16_t* __restrict__ vt,
                                              float* __restrict__ outp,
                                              float* __restrict__ lpart) {
  __shared__ __align__(16) bf16_t Ks[2][64 * 64];   // K tile, rows=key, XOR-swizzled
  __shared__ __align__(16) bf16_t Vs[2][64 * 64];   // V^T tile (pre-permuted cols)
  const int tid  = threadIdx.x;
  const int wave = tid >> 6, lane = tid & 63;
  const int g = lane >> 4, c = lane & 15;
  const int qt = blockIdx.x;           // 32 q-tiles of 64 rows
  const int bh = blockIdx.y;           // 24
  const int z  = (SPLIT > 1) ? blockIdx.z : 0;
  const int b = bh / H_, h = bh - b * H_;
  const int r0 = z * (T_ / SPLIT);     // key-range base

  // hoisted Q fragments: lane holds Q[q = c][d = 8g..8g+7 (+32)] (pre-scaled)
  v8bf aq[2];
  {
    const bf16_t* qb = qkv + ((size_t)(b * T_ + qt * 64 + wave * 16 + c)) * N3_ + h * DH_ + g * 8;
    aq[0] = *(const v8bf*)qb;
    aq[1] = *(const v8bf*)(qb + 32);
  }
  float lsum = 0.f;
  const f32x4 zf = {0.f, 0.f, 0.f, 0.f};
  f32x4 oacc[4];                            // O^T[d = ni*16+g*4+j][q = c]
  #pragma unroll
  for (int ni = 0; ni < 4; ++ni) oacc[ni] = zf;

  // staging pointers (pre-swizzled global source, linear LDS dest — rule #21)
  const int rS  = tid >> 3;   // 0..31
  const int grS = tid & 7;
  const bf16_t* gK[2];
  const bf16_t* gV[2];
  #pragma unroll
  for (int cc = 0; cc < 2; ++cc) {
    int r    = cc * 32 + rS;
    int colk = ((grS ^ (r & 7)) << 3);
    gK[cc] = qkv + ((size_t)(b * T_ + r0 + r)) * N3_ + D_ + h * DH_ + colk;
    gV[cc] = vt + ((size_t)(bh * DH_ + r)) * T_ + r0 + colk;
  }

  // prologue: stage tile 0 into buf 0
  #pragma unroll
  for (int cc = 0; cc < 2; ++cc) {
    gll16(gK[cc], (char*)Ks[0] + cc * 4096 + wave * 1024);
    gll16(gV[cc], (char*)Vs[0] + cc * 4096 + wave * 1024);
    gK[cc] += 64 * (size_t)N3_;
    gV[cc] += 64;
  }
  __syncthreads();

#define ATTN_BODY(CUR, NXT, DOSTAGE)                                          \
  {                                                                           \
    if (DOSTAGE) {                                                            \
      _Pragma("unroll")                                                       \
      for (int cc = 0; cc < 2; ++cc) {                                        \
        gll16(gK[cc], (char*)Ks[NXT] + cc * 4096 + wave * 1024);              \
        gll16(gV[cc], (char*)Vs[NXT] + cc * 4096 + wave * 1024);              \
        gK[cc] += 64 * (size_t)N3_;                                           \
        gV[cc] += 64;                                                         \
      }                                                                       \
    }                                                                         \
    f32x4 s[4] = {zf, zf, zf, zf};                                            \
    __builtin_amdgcn_s_setprio(1);                                            \
    _Pragma("unroll")                                                         \
    for (int kk = 0; kk < 2; ++kk) {                                          \
      _Pragma("unroll")                                                       \
      for (int ni = 0; ni < 4; ++ni) {                                        \
        const int row = ni * 16 + c;                                          \
        v8bf bk = *(const v8bf*)(Ks[CUR] + row * 64 +                         \
                                 ((kk * 32 + g * 8) ^ ((row & 7) << 3)));     \
        s[ni] = __builtin_amdgcn_mfma_f32_16x16x32_bf16(bk, aq[kk], s[ni], 0, 0, 0); \
      }                                                                       \
    }                                                                         \
    __builtin_amdgcn_s_setprio(0);                                            \
    float rsub = 0.f;                                                         \
    v8bf apk[2];                                                              \
    _Pragma("unroll")                                                         \
    for (int ni = 0; ni < 4; ++ni) {                                          \
      float p0 = __builtin_amdgcn_exp2f(s[ni][0]);                            \
      float p1 = __builtin_amdgcn_exp2f(s[ni][1]);                            \
      float p2 = __builtin_amdgcn_exp2f(s[ni][2]);                            \
      float p3 = __builtin_amdgcn_exp2f(s[ni][3]);                            \
      rsub += (p0 + p1) + (p2 + p3);                                          \
      const int kkh = ni >> 1, off = (ni & 1) * 4;                            \
      apk[kkh][off + 0] = (bf16_t)p0;                                         \
      apk[kkh][off + 1] = (bf16_t)p1;                                         \
      apk[kkh][off + 2] = (bf16_t)p2;                                         \
      apk[kkh][off + 3] = (bf16_t)p3;                                         \
    }                                                                         \
    lsum += rsub;                                                             \
    __builtin_amdgcn_s_setprio(1);                                            \
    _Pragma("unroll")                                                         \
    for (int kk = 0; kk < 2; ++kk) {                                          \
      _Pragma("unroll")                                                       \
      for (int ni = 0; ni < 4; ++ni) {                                        \
        const int row = ni * 16 + c;                                          \
        v8bf bv = *(const v8bf*)(Vs[CUR] + row * 64 +                         \
                                 ((kk * 32 + g * 8) ^ ((row & 7) << 3)));     \
        oacc[ni] = __builtin_amdgcn_mfma_f32_16x16x32_bf16(bv, apk[kk], oacc[ni], 0, 0, 0); \
      }                                                                       \
    }                                                                         \
    __builtin_amdgcn_s_setprio(0);                                            \
    __syncthreads();                                                          \
  }

  // NT tiles, unrolled x2 with static buffer indices
  const int NT2 = T_ / (64 * SPLIT * 2);
  for (int kt2 = 0; kt2 < NT2; ++kt2) {
    ATTN_BODY(0, 1, true)
    ATTN_BODY(1, 0, (kt2 < NT2 - 1))
  }
#undef ATTN_BODY

  // epilogue
  lsum += __shfl_xor(lsum, 16);
  lsum += __shfl_xor(lsum, 32);
  const float inv = 1.0f / lsum;
  const int q = qt * 64 + wave * 16 + c;
  if (SPLIT > 1) {
    if (g == 0) lpart[(size_t)z * (B_ * H_ * T_) + (b * H_ + h) * T_ + q] = lsum;
    bf16_t* ob = (bf16_t*)outp + ((size_t)z * M_ * D_ + ((size_t)(b * T_ + q)) * D_ + h * DH_);
    #pragma unroll
    for (int ni = 0; ni < 4; ++ni) {
      v4bf o4 = {(bf16_t)(oacc[ni][0] * inv), (bf16_t)(oacc[ni][1] * inv),
                 (bf16_t)(oacc[ni][2] * inv), (bf16_t)(oacc[ni][3] * inv)};
      *(v4bf*)(ob + ni * 16 + g * 4) = o4;
    }
  } else {
    float* ob = outp + ((size_t)(b * T_ + q)) * D_ + h * DH_;
    #pragma unroll
    for (int ni = 0; ni < 4; ++ni) {
      float4 o4 = {oacc[ni][0] * inv, oacc[ni][1] * inv, oacc[ni][2] * inv, oacc[ni][3] * inv};
      *(float4*)(ob + ni * 16 + g * 4) = o4;
    }
  }
}

extern "C" void kernel_launch(void* const* d_in, const int* in_sizes, int n_in,
                              void* d_out, int out_size, void* d_ws, size_t ws_size,
                              hipStream_t stream) {
  const float* x    = (const float*)d_in[0];
  const float* W    = (const float*)d_in[1];
  const float* bias = (const float*)d_in[2];
  float* out = (float*)d_out;
  char* ws = (char*)d_ws;
  bf16_t* xb    = (bf16_t*)(ws);                 // 4096*768*2   = 6,291,456
  bf16_t* wt    = (bf16_t*)(ws + 6291456);       // 2304*768*2   = 3,538,944
  bf16_t* qkvb  = (bf16_t*)(ws + 9830400);       // 4096*2304*2  = 18,874,368
  bf16_t* vtb   = (bf16_t*)(ws + 28704768);      // 24*64*2048*2 = 6,291,456

  k_conv_x <<<dim3(3072),    dim3(256), 0, stream>>>(x, xb, (M_ * D_) / 4);
  k_conv_wt<<<dim3(36, 12),  dim3(256), 0, stream>>>(W, wt);
  k_gemm   <<<dim3(18, 32),  dim3(256), 0, stream>>>(xb, wt, bias, qkvb, vtb);
  k_attn<1><<<dim3(32, 24),  dim3(256), 0, stream>>>(qkvb, vtb, out, nullptr);
}